// Round 3
// baseline (69.494 us; speedup 1.0000x reference)
//
#include <hip/hip_runtime.h>
#include <math.h>

// Problem: out_matrix, label_matrix [n=64, n=64, B=256] f32.
// loss = sum_{b,r,j,k} relu(m - (o[r,j,b]-o[r,k,b])*(l[r,j,b]-l[r,k,b]))
// Symmetric in (j,k); diagonal = relu(m): loss = 2*S_upper + N*N*B*relu(m).
// cnt = #{(b,r): argmax_j o[r,j,b] == argmax_j l[r,j,b]}

constexpr int N = 64;        // n
constexpr int B = 256;       // batch (contiguous innermost)
constexpr int BCHUNK = 64;   // b's per block (== wave width; jg wave-uniform)
constexpr int NJG = 8;       // j-groups (one per wave)
constexpr int JG = 8;        // j's per thread: j_i = jg + 8*i
constexpr int THREADS = BCHUNK * NJG;    // 512
constexpr int NBLK = N * (B / BCHUNK);   // 256 partials

__global__ __launch_bounds__(THREADS)
void pm_hinge_partial(const float* __restrict__ outm,
                      const float* __restrict__ labm,
                      const float* __restrict__ margin,
                      float* __restrict__ ws)
{
    // Interleaved (o,l) pairs: [j][b] float2, 32 KB. One ds_read_b64 per k.
    __shared__ float2 ol[N * BCHUNK];
    __shared__ float wsum[NJG];

    const int r   = blockIdx.x;
    const int b0  = blockIdx.y * BCHUNK;
    const int t   = threadIdx.x;
    const int blk = blockIdx.y * N + r;

    // Stage global -> LDS. 1024 float4-pairs; interleave into float2 lanes,
    // written as two b128 stores per pair.
    const float* src_o = outm + (size_t)r * (N * B) + b0;
    const float* src_l = labm + (size_t)r * (N * B) + b0;
#pragma unroll
    for (int f = t; f < (N * BCHUNK) / 4; f += THREADS) {
        const int j  = f >> 4;
        const int b4 = (f & 15) * 4;
        const float4 vo = *(const float4*)(src_o + j * B + b4);
        const float4 vl = *(const float4*)(src_l + j * B + b4);
        float4 p0 = make_float4(vo.x, vl.x, vo.y, vl.y);
        float4 p1 = make_float4(vo.z, vl.z, vo.w, vl.w);
        *(float4*)(&ol[j * BCHUNK + b4])     = p0;
        *(float4*)(&ol[j * BCHUNK + b4 + 2]) = p1;
    }
    __syncthreads();

    const float mg = margin[0];
    const int   b  = t & 63;   // lane id == b
    const int   jg = t >> 6;   // wave id == j-group (wave-uniform)

    // Register-cache this thread's 8 j-row (o,l) values.
    float oj[JG], lj[JG];
#pragma unroll
    for (int i = 0; i < JG; ++i) {
        const float2 v = ol[(jg + NJG * i) * BCHUNK + b];
        oj[i] = v.x; lj[i] = v.y;
    }

    // Strict upper triangle, balanced by strided j-assignment.
    // Regime m (0..7): k in (jg+8m, jg+8m+8] has exactly m+1 of this
    // thread's j's with j < k (j == jg mod 8). m=7 clips at k=63.
    // All loop bounds wave-uniform.
    float acc = 0.0f;
#pragma unroll
    for (int m = 0; m < 7; ++m) {
#pragma unroll
        for (int kk = 1; kk <= 8; ++kk) {
            const int k = jg + 8 * m + kk;
            const float2 olk = ol[k * BCHUNK + b];   // one b64 read
#pragma unroll
            for (int i = 0; i <= m; ++i)
                acc += fmaxf(fmaf(-(oj[i] - olk.x), lj[i] - olk.y, mg), 0.0f);
        }
    }
    for (int k = jg + 57; k < N; ++k) {              // 7-jg iters, wave-uniform
        const float2 olk = ol[k * BCHUNK + b];
#pragma unroll
        for (int i = 0; i < JG; ++i)
            acc += fmaxf(fmaf(-(oj[i] - olk.x), lj[i] - olk.y, mg), 0.0f);
    }

    // argmax-equality count (wave 0 only; one b64 read serves both argmaxes).
    float cnt = 0.0f;
    if (t < 64) {
        const int bb = t;
        float2 v0 = ol[bb];
        float bo = v0.x; int io = 0;
        float bl = v0.y; int il = 0;
#pragma unroll 4
        for (int j = 1; j < N; ++j) {
            const float2 v = ol[j * BCHUNK + bb];
            if (v.x > bo) { bo = v.x; io = j; }
            if (v.y > bl) { bl = v.y; il = j; }
        }
        const unsigned long long mask = __ballot(io == il);
        cnt = (float)__popcll(mask);
    }

    // Per-wave shuffle reduce, then per-block sum -> partials in ws.
#pragma unroll
    for (int off = 32; off > 0; off >>= 1)
        acc += __shfl_down(acc, off, 64);
    if (b == 0) wsum[jg] = acc;
    __syncthreads();
    if (t == 0) {
        float s = 0.0f;
#pragma unroll
        for (int w = 0; w < NJG; ++w) s += wsum[w];
        ws[blk] = s;             // upper-triangle partial
        ws[NBLK + blk] = cnt;    // argmax-equality partial
    }
}

// One wave: fold 256+256 partials, apply symmetry factor + diagonal.
__global__ __launch_bounds__(64)
void pm_hinge_reduce(const float* __restrict__ ws,
                     const float* __restrict__ margin,
                     float* __restrict__ dout)
{
    const int t = threadIdx.x;
    float s = 0.0f, c = 0.0f;
#pragma unroll
    for (int i = 0; i < NBLK / 64; ++i) {
        s += ws[t + 64 * i];
        c += ws[NBLK + t + 64 * i];
    }
#pragma unroll
    for (int off = 32; off > 0; off >>= 1) {
        s += __shfl_down(s, off, 64);
        c += __shfl_down(c, off, 64);
    }
    if (t == 0) {
        const float m = margin[0];
        dout[0] = 2.0f * s + (float)(N * (size_t)N * B) * fmaxf(m, 0.0f);
        dout[1] = c;
    }
}

extern "C" void kernel_launch(void* const* d_in, const int* in_sizes, int n_in,
                              void* d_out, int out_size, void* d_ws, size_t ws_size,
                              hipStream_t stream) {
    const float* outm   = (const float*)d_in[0];
    const float* labm   = (const float*)d_in[1];
    const float* margin = (const float*)d_in[2];
    float* out = (float*)d_out;
    float* ws  = (float*)d_ws;

    pm_hinge_partial<<<dim3(N, B / BCHUNK), THREADS, 0, stream>>>(outm, labm, margin, ws);
    pm_hinge_reduce<<<1, 64, 0, stream>>>(ws, margin, out);
}